// Round 2
// baseline (9.671 us; speedup 1.0000x reference)
//
#include <hip/hip_runtime.h>

// SE(3) exponential from two tiny MLPs, applied to a 4x4 matrix.
// Single block, single wave (64 lanes). Each lane handles 8 of the 512
// hidden units for BOTH MLPs. All global loads are issued up front so the
// full memory latency is paid once, overlapped. Butterfly __shfl_xor
// reduction gives every lane the 6 dot-product sums; all lanes redundantly
// compute the 3x3 Rodrigues math; lanes 0..15 write one element each of
// exp_i @ x.
__global__ __launch_bounds__(64)
void se3_mlp_kernel(const float* __restrict__ x,      // (4,4)
                    const float* __restrict__ t,      // (1,)
                    const float* __restrict__ W1,     // (512,1)
                    const float* __restrict__ Wb1,    // (512,)
                    const float* __restrict__ W2,     // (3,512)
                    const float* __restrict__ Wb2,    // (3,)
                    const float* __restrict__ V1,     // (512,1)
                    const float* __restrict__ Vb1,    // (512,)
                    const float* __restrict__ V2,     // (3,512)
                    const float* __restrict__ Vb2,    // (3,)
                    const float* __restrict__ theta_p,// scalar
                    float* __restrict__ out)          // (4,4)
{
    const int lane = threadIdx.x;          // 0..63
    const int base = lane * 8;             // this lane's 8 hidden units

    // ---- issue ALL global loads up front (independent, overlap latency) ----
    const float tv  = t[0];
    const float th  = theta_p[0];

    float4 w1a = *(const float4*)(W1  + base);
    float4 w1b = *(const float4*)(W1  + base + 4);
    float4 wb1a = *(const float4*)(Wb1 + base);
    float4 wb1b = *(const float4*)(Wb1 + base + 4);
    float4 w2r[3][2];
    #pragma unroll
    for (int j = 0; j < 3; ++j) {
        w2r[j][0] = *(const float4*)(W2 + j * 512 + base);
        w2r[j][1] = *(const float4*)(W2 + j * 512 + base + 4);
    }
    float4 v1a = *(const float4*)(V1  + base);
    float4 v1b = *(const float4*)(V1  + base + 4);
    float4 vb1a = *(const float4*)(Vb1 + base);
    float4 vb1b = *(const float4*)(Vb1 + base + 4);
    float4 v2r[3][2];
    #pragma unroll
    for (int j = 0; j < 3; ++j) {
        v2r[j][0] = *(const float4*)(V2 + j * 512 + base);
        v2r[j][1] = *(const float4*)(V2 + j * 512 + base + 4);
    }
    const float wb2_0 = Wb2[0], wb2_1 = Wb2[1], wb2_2 = Wb2[2];
    const float vb2_0 = Vb2[0], vb2_1 = Vb2[1], vb2_2 = Vb2[2];
    // x column for this lane's output element (lanes 0..15)
    const int r   = (lane & 15) >> 2;
    const int col = lane & 3;
    const float xc0 = x[0 * 4 + col];
    const float xc1 = x[1 * 4 + col];
    const float xc2 = x[2 * 4 + col];
    const float xc3 = x[3 * 4 + col];

    // ---- W-MLP hidden + output partials ----
    float hw[8];
    hw[0] = fmaxf(0.f, fmaf(w1a.x, tv, wb1a.x));
    hw[1] = fmaxf(0.f, fmaf(w1a.y, tv, wb1a.y));
    hw[2] = fmaxf(0.f, fmaf(w1a.z, tv, wb1a.z));
    hw[3] = fmaxf(0.f, fmaf(w1a.w, tv, wb1a.w));
    hw[4] = fmaxf(0.f, fmaf(w1b.x, tv, wb1b.x));
    hw[5] = fmaxf(0.f, fmaf(w1b.y, tv, wb1b.y));
    hw[6] = fmaxf(0.f, fmaf(w1b.z, tv, wb1b.z));
    hw[7] = fmaxf(0.f, fmaf(w1b.w, tv, wb1b.w));

    float hv[8];
    hv[0] = fmaxf(0.f, fmaf(v1a.x, tv, vb1a.x));
    hv[1] = fmaxf(0.f, fmaf(v1a.y, tv, vb1a.y));
    hv[2] = fmaxf(0.f, fmaf(v1a.z, tv, vb1a.z));
    hv[3] = fmaxf(0.f, fmaf(v1a.w, tv, vb1a.w));
    hv[4] = fmaxf(0.f, fmaf(v1b.x, tv, vb1b.x));
    hv[5] = fmaxf(0.f, fmaf(v1b.y, tv, vb1b.y));
    hv[6] = fmaxf(0.f, fmaf(v1b.z, tv, vb1b.z));
    hv[7] = fmaxf(0.f, fmaf(v1b.w, tv, vb1b.w));

    float wsum[3], vsum[3];
    #pragma unroll
    for (int j = 0; j < 3; ++j) {
        float a = 0.f;
        a = fmaf(w2r[j][0].x, hw[0], a);
        a = fmaf(w2r[j][0].y, hw[1], a);
        a = fmaf(w2r[j][0].z, hw[2], a);
        a = fmaf(w2r[j][0].w, hw[3], a);
        a = fmaf(w2r[j][1].x, hw[4], a);
        a = fmaf(w2r[j][1].y, hw[5], a);
        a = fmaf(w2r[j][1].z, hw[6], a);
        a = fmaf(w2r[j][1].w, hw[7], a);
        wsum[j] = a;
        float b = 0.f;
        b = fmaf(v2r[j][0].x, hv[0], b);
        b = fmaf(v2r[j][0].y, hv[1], b);
        b = fmaf(v2r[j][0].z, hv[2], b);
        b = fmaf(v2r[j][0].w, hv[3], b);
        b = fmaf(v2r[j][1].x, hv[4], b);
        b = fmaf(v2r[j][1].y, hv[5], b);
        b = fmaf(v2r[j][1].z, hv[6], b);
        b = fmaf(v2r[j][1].w, hv[7], b);
        vsum[j] = b;
    }

    // ---- butterfly reduction across the wave (all lanes get full sums) ----
    #pragma unroll
    for (int off = 32; off > 0; off >>= 1) {
        #pragma unroll
        for (int j = 0; j < 3; ++j) {
            wsum[j] += __shfl_xor(wsum[j], off);
            vsum[j] += __shfl_xor(vsum[j], off);
        }
    }

    const float w0 = wsum[0] + wb2_0;
    const float w1 = wsum[1] + wb2_1;
    const float w2 = wsum[2] + wb2_2;
    const float v0 = vsum[0] + vb2_0;
    const float v1 = vsum[1] + vb2_1;
    const float v2 = vsum[2] + vb2_2;

    // ---- Rodrigues / SE(3) exponential (all lanes, redundant) ----
    const float s   = sinf(th);
    const float c   = cosf(th);
    const float omc = 1.f - c;   // 1 - cos
    const float tms = th - s;    // theta - sin

    float ss[3][3]  = {{0.f, -w2,  w1},
                       { w2, 0.f, -w0},
                       {-w1,  w0, 0.f}};
    float ss2[3][3];
    ss2[0][0] = -(w1*w1 + w2*w2);
    ss2[0][1] =   w0*w1;
    ss2[0][2] =   w0*w2;
    ss2[1][0] =   w0*w1;
    ss2[1][1] = -(w0*w0 + w2*w2);
    ss2[1][2] =   w1*w2;
    ss2[2][0] =   w0*w2;
    ss2[2][1] =   w1*w2;
    ss2[2][2] = -(w0*w0 + w1*w1);

    float R[3][3], Vm[3][3];
    #pragma unroll
    for (int i = 0; i < 3; ++i) {
        #pragma unroll
        for (int j = 0; j < 3; ++j) {
            const float eye = (i == j) ? 1.f : 0.f;
            R[i][j]  = eye + s * ss[i][j] + omc * ss2[i][j];
            Vm[i][j] = th * eye + omc * ss[i][j] + tms * ss2[i][j];
        }
    }
    float trans[3];
    #pragma unroll
    for (int i = 0; i < 3; ++i)
        trans[i] = Vm[i][0] * v0 + Vm[i][1] * v1 + Vm[i][2] * v2;

    // ---- out = exp_i @ x ; lanes 0..15 write one element each ----
    if (lane < 16) {
        float er0, er1, er2, er3;
        if (r < 3) { er0 = R[r][0]; er1 = R[r][1]; er2 = R[r][2]; er3 = trans[r]; }
        else       { er0 = 0.f;     er1 = 0.f;     er2 = 0.f;     er3 = 1.f; }
        const float o = er0 * xc0 + er1 * xc1 + er2 * xc2 + er3 * xc3;
        out[r * 4 + col] = o;
    }
}

extern "C" void kernel_launch(void* const* d_in, const int* in_sizes, int n_in,
                              void* d_out, int out_size, void* d_ws, size_t ws_size,
                              hipStream_t stream) {
    const float* x     = (const float*)d_in[0];
    const float* t     = (const float*)d_in[1];
    const float* W1    = (const float*)d_in[2];
    const float* Wb1   = (const float*)d_in[3];
    const float* W2    = (const float*)d_in[4];
    const float* Wb2   = (const float*)d_in[5];
    const float* V1    = (const float*)d_in[6];
    const float* Vb1   = (const float*)d_in[7];
    const float* V2    = (const float*)d_in[8];
    const float* Vb2   = (const float*)d_in[9];
    const float* theta = (const float*)d_in[10];
    float* out = (float*)d_out;

    se3_mlp_kernel<<<1, 64, 0, stream>>>(x, t, W1, Wb1, W2, Wb2,
                                         V1, Vb1, V2, Vb2, theta, out);
}